// Round 2
// baseline (193.572 us; speedup 1.0000x reference)
//
#include <hip/hip_runtime.h>
#include <math.h>

// Rolling stats: W=64 window over (N=262144, F=32) fp32, stride 1, VALID.
// Out row t (t < N-63): [mean(32) | std(32) | min(32) | max(32) | sum(32)].
//
// R7 structure: store-stream overhaul (the only component invariant across
// the R5/R6 neutral pair, hence the inferred bottleneck).
//  - R5 (3 blk/CU) == R6 (8 blk/CU) to 0.16% despite 3x LDS / 2x VALU /
//    1.6x load-count differences => kernel (~84us of the 184us; the other
//    ~100us is the 671MB poison fill) is bound by neither occupancy nor
//    on-chip pipes. Invariant = 42M scalar dword stores, 167.7MB at an
//    effective ~2.0 TB/s (fill demonstrates 6.65 TB/s write drain).
//  - Fix: 4 columns/thread -> each stat stored as one float4
//    (global_store_dwordx4, 1KB/wave-instr, 164K instrs instead of 655K),
//    and NON-TEMPORAL stores: output is write-once/never-read; nt keeps
//    167MB of streaming writes from churning L2 against the input reads.
//  - Block = 256 threads = 8 col-groups x 32 row-chunks, RCH=8 =>
//    256 output rows/block, stage 320 rows (40KB LDS), 1024 blocks,
//    overlap re-fetch 1.25x. LDS b128 reads are volume-bound per
//    quarter-wave (2 dwords/bank), no swizzle needed.
//  - smin/smax = vf4[8] (64 floats) is fine: occupancy proven irrelevant.
//    __launch_bounds__(256,3) for spill-free ~168 VGPR cap.

typedef float vf4 __attribute__((ext_vector_type(4)));

#define WINW 64
#define RCH 8
#define NF 32
#define ROWS_PER_BLK 256
#define STAGE_ROWS (ROWS_PER_BLK + WINW)  // 320

__device__ __forceinline__ vf4 v4min(vf4 a, vf4 b) {
  vf4 r;
  r.x = fminf(a.x, b.x); r.y = fminf(a.y, b.y);
  r.z = fminf(a.z, b.z); r.w = fminf(a.w, b.w);
  return r;
}
__device__ __forceinline__ vf4 v4max(vf4 a, vf4 b) {
  vf4 r;
  r.x = fmaxf(a.x, b.x); r.y = fmaxf(a.y, b.y);
  r.z = fmaxf(a.z, b.z); r.w = fmaxf(a.w, b.w);
  return r;
}
__device__ __forceinline__ vf4 v4fma(vf4 a, vf4 b, vf4 c) {
  vf4 r;
  r.x = fmaf(a.x, b.x, c.x); r.y = fmaf(a.y, b.y, c.y);
  r.z = fmaf(a.z, b.z, c.z); r.w = fmaf(a.w, b.w, c.w);
  return r;
}
__device__ __forceinline__ vf4 v4sqrt(vf4 a) {
  vf4 r;
  r.x = sqrtf(a.x); r.y = sqrtf(a.y);
  r.z = sqrtf(a.z); r.w = sqrtf(a.w);
  return r;
}

__global__ __launch_bounds__(256, 3) void rolling_stats_kernel(
    const float* __restrict__ x, float* __restrict__ out, int N, int T_out) {
  __shared__ vf4 tile[STAGE_ROWS * 8];  // 40960 B, row r = 8 vf4

  int t0_blk = blockIdx.x * ROWS_PER_BLK;

  // --- Stage: 320 rows x 8 vf4 = 2560 vf4, 10 per thread, coalesced. ---
  const vf4* xv = (const vf4*)x;
#pragma unroll
  for (int it = 0; it < (STAGE_ROWS * 8) / 256; ++it) {  // 10 iters
    int f = it * 256 + (int)threadIdx.x;
    int r = f >> 3;            // local row
    int q = f & 7;             // vf4 col
    int gr = t0_blk + r;
    gr = gr < N ? gr : N - 1;  // clamp (tail block; stores guarded)
    tile[f] = xv[(size_t)gr * 8 + q];
  }
  __syncthreads();

  // --- Per-thread sliding window: 4 columns x 8 output rows. ---
  int g = (int)threadIdx.x & 7;             // col group: cols 4g..4g+3
  int lr0 = ((int)threadIdx.x >> 3) * RCH;  // local first output row
  int t0 = t0_blk + lr0;
  const vf4* tc = tile + g;

  vf4 smin[RCH], smax[RCH];  // suffix min/max of first window
  vf4 ssum = {0.f, 0.f, 0.f, 0.f};
  vf4 ssq = {0.f, 0.f, 0.f, 0.f};
  vf4 rmin = {INFINITY, INFINITY, INFINITY, INFINITY};
  vf4 rmax = {-INFINITY, -INFINITY, -INFINITY, -INFINITY};

  // Pass 1: reverse scan of first window rows lr0+63 .. lr0.
#pragma unroll
  for (int j = WINW - 1; j >= 0; --j) {
    vf4 a = tc[(lr0 + j) * 8];
    rmin = v4min(rmin, a);
    rmax = v4max(rmax, a);
    ssum += a;
    ssq = v4fma(a, a, ssq);
    if (j < RCH) {  // constant predicate after unroll
      smin[j] = rmin;
      smax[j] = rmax;
    }
  }

  // Pass 2: forward over the chunk's 8 outputs.
  vf4 pmin = {INFINITY, INFINITY, INFINITY, INFINITY};
  vf4 pmax = {-INFINITY, -INFINITY, -INFINITY, -INFINITY};
  vf4 wsum = ssum, wsq = ssq;
  float* ob = out + (size_t)t0 * (5 * NF) + 4 * g;
#pragma unroll
  for (int j = 0; j < RCH; ++j) {
    if (j > 0) {
      vf4 b = tc[(lr0 + WINW - 1 + j) * 8];  // incoming row
      vf4 a = tc[(lr0 + j - 1) * 8];         // outgoing row
      pmin = v4min(pmin, b);
      pmax = v4max(pmax, b);
      wsum += b - a;
      wsq = v4fma(b, b, wsq);
      wsq = v4fma(-a, a, wsq);
    }
    if (t0 + j < T_out) {
      vf4 wmin = v4min(smin[j], pmin);
      vf4 wmax = v4max(smax[j], pmax);
      vf4 mean = wsum * 0.015625f;                        // /64
      vf4 var = v4fma(-mean, mean, wsq * 0.015625f);      // E[x^2]-E[x]^2
      vf4 zero = {0.f, 0.f, 0.f, 0.f};
      var = v4max(var, zero);
      vf4 sd = v4sqrt(var);
      float* orow = ob + (size_t)j * (5 * NF);
      __builtin_nontemporal_store(mean, (vf4*)(orow + 0 * NF));
      __builtin_nontemporal_store(sd,   (vf4*)(orow + 1 * NF));
      __builtin_nontemporal_store(wmin, (vf4*)(orow + 2 * NF));
      __builtin_nontemporal_store(wmax, (vf4*)(orow + 3 * NF));
      __builtin_nontemporal_store(wsum, (vf4*)(orow + 4 * NF));
    }
  }
}

extern "C" void kernel_launch(void* const* d_in, const int* in_sizes, int n_in,
                              void* d_out, int out_size, void* d_ws,
                              size_t ws_size, hipStream_t stream) {
  const float* x = (const float*)d_in[0];
  float* out = (float*)d_out;
  int N = in_sizes[0] / NF;    // 262144 rows
  int T_out = N - (WINW - 1);  // 262081 output rows
  int nblocks = (T_out + ROWS_PER_BLK - 1) / ROWS_PER_BLK;  // 1024
  rolling_stats_kernel<<<nblocks, 256, 0, stream>>>(x, out, N, T_out);
}

// Round 3
// 184.635 us; speedup vs baseline: 1.0484x; 1.0484x over previous
//
#include <hip/hip_runtime.h>
#include <math.h>

// Rolling stats: W=64 window over (N=262144, F=32) fp32, stride 1, VALID.
// Out row t (t < N-63): [mean(32) | std(32) | min(32) | max(32) | sum(32)].
//
// R8 structure: fill-shaped writeout experiment.
//  - Evidence chain: R5(3blk/CU,160VGPR) == R6(8blk/CU,64VGPR) == 184us
//    despite 3x LDS / 2x VALU / 2.7x occupancy differences -> kernel
//    (~84us; other ~100us is the harness's 671MB poison fill at 6.65TB/s)
//    is bound by the memory system, not on-chip pipes. R7 (vf4+nt,
//    8-scattered-segment stores) = 193.6us (+9) -> store-stream shape DOES
//    move the needle, and scatter/nt made it worse.
//  - Hypothesis: the 5-plane x 640B-strided scattered store pattern is why
//    effective mixed BW is ~2.4TB/s vs the fill's 6.65TB/s on the same
//    buffer. Test: make the store stream IDENTICAL in shape to the fill.
//  - Phase 1: stage 128 input rows -> LDS (16KB), float4 coalesced (R6).
//  - Phase 2: R6 compute (RCH=8, 8 chunks x 32 cols, 64 output rows), but
//    results go to an LDS output tile (64 rows x 160 floats = 40KB).
//    Bank: dword = row*160 + stat*32 + c, 160%32==0 -> bank = c.
//    Lanes 0..31 distinct banks, 2-way across half-wave = free (m136).
//  - Phase 3: linear LDS->global copy: lane i stores blockbase + 16*i,
//    10 x global_store_dwordx4/thread, each wave = contiguous aligned 1KB,
//    monotone addresses — exactly the fill's pattern. No nt (R7 lesson).
//    LDS b128 reads linear: quarter-wave = 64 dwords = 2/bank, volume-
//    bound, conflict-free.
//  - LDS 57.3KB -> 2 blocks/CU (8 waves/CU): fine, occupancy proven
//    irrelevant by R5==R6.

typedef float vf4 __attribute__((ext_vector_type(4)));

#define WINW 64
#define RCH 8
#define NF 32
#define ROWS_PER_BLK 64                      // output rows per block
#define STAGE_ROWS (ROWS_PER_BLK + WINW)     // 128 input rows staged
#define OUT_F4_PER_BLK (ROWS_PER_BLK * 40)   // 2560 float4 = 40KB

__global__ __launch_bounds__(256, 2) void rolling_stats_kernel(
    const float* __restrict__ x, float* __restrict__ out, int N, int T_out) {
  __shared__ float itile[STAGE_ROWS * NF];       // 16384 B
  __shared__ float otile[ROWS_PER_BLK * 5 * NF]; // 40960 B

  int t0_blk = blockIdx.x * ROWS_PER_BLK;

  // --- Phase 1: stage 128 rows x 32 floats = 1024 float4, coalesced. ---
  const vf4* xv = (const vf4*)x;  // row r = 8 vf4
  vf4* tv = (vf4*)itile;
#pragma unroll
  for (int it = 0; it < (STAGE_ROWS * NF / 4) / 256; ++it) {  // 4 iters
    int f = it * 256 + (int)threadIdx.x;
    int r = f >> 3;            // local row
    int gr = t0_blk + r;
    gr = gr < N ? gr : N - 1;  // clamp (tail block; stores guarded later)
    tv[f] = xv[(size_t)gr * 8 + (f & 7)];
  }
  __syncthreads();

  // --- Phase 2: per-thread sliding window, results into LDS otile. ---
  int c = (int)threadIdx.x & (NF - 1);
  int lr0 = ((int)threadIdx.x >> 5) * RCH;  // local first output row
  const float* tc = itile + c;

  float smin[RCH], smax[RCH];
  float ssum = 0.f, ssq = 0.f;
  float rmin = INFINITY, rmax = -INFINITY;

  // Reverse scan of first window rows lr0+63 .. lr0.
#pragma unroll
  for (int j = WINW - 1; j >= RCH; --j) {
    float a = tc[(lr0 + j) * NF];
    rmin = fminf(rmin, a);
    rmax = fmaxf(rmax, a);
    ssum += a;
    ssq = fmaf(a, a, ssq);
  }
#pragma unroll
  for (int j = RCH - 1; j >= 0; --j) {
    float a = tc[(lr0 + j) * NF];
    rmin = fminf(rmin, a);
    rmax = fmaxf(rmax, a);
    ssum += a;
    ssq = fmaf(a, a, ssq);
    smin[j] = rmin;
    smax[j] = rmax;
  }

  // Forward over the chunk's 8 outputs; write stats into otile.
  float pmin = INFINITY, pmax = -INFINITY;
  float wsum = ssum, wsq = ssq;
  float* oc = otile + lr0 * (5 * NF) + c;
#pragma unroll
  for (int j = 0; j < RCH; ++j) {
    if (j > 0) {
      float bnew = tc[(lr0 + WINW - 1 + j) * NF];  // incoming row
      float aold = tc[(lr0 + j - 1) * NF];         // outgoing row
      pmin = fminf(pmin, bnew);
      pmax = fmaxf(pmax, bnew);
      wsum += bnew - aold;
      wsq = fmaf(bnew, bnew, wsq);
      wsq = fmaf(-aold, aold, wsq);
    }
    float wmin = fminf(smin[j], pmin);
    float wmax = fmaxf(smax[j], pmax);
    float mean = wsum * 0.015625f;                   // /64
    float var = fmaf(-mean, mean, wsq * 0.015625f);  // E[x^2]-E[x]^2
    var = fmaxf(var, 0.f);
    float sd = sqrtf(var);
    float* orow = oc + j * (5 * NF);  // bank = c for every plane
    orow[0 * NF] = mean;
    orow[1 * NF] = sd;
    orow[2 * NF] = wmin;
    orow[3 * NF] = wmax;
    orow[4 * NF] = wsum;
  }
  __syncthreads();

  // --- Phase 3: fill-shaped linear writeout. ---
  // Lane i -> blockbase + 16B*i; each wave = contiguous aligned 1KB.
  const vf4* ov = (const vf4*)otile;
  vf4* outv = (vf4*)out;
  size_t base = (size_t)blockIdx.x * OUT_F4_PER_BLK;
  size_t limit = (size_t)T_out * 40;  // valid float4 count in out
#pragma unroll
  for (int it = 0; it < OUT_F4_PER_BLK / 256; ++it) {  // 10 iters
    int f = it * 256 + (int)threadIdx.x;
    size_t g = base + (size_t)f;
    if (g < limit) outv[g] = ov[f];
  }
}

extern "C" void kernel_launch(void* const* d_in, const int* in_sizes, int n_in,
                              void* d_out, int out_size, void* d_ws,
                              size_t ws_size, hipStream_t stream) {
  const float* x = (const float*)d_in[0];
  float* out = (float*)d_out;
  int N = in_sizes[0] / NF;    // 262144 rows
  int T_out = N - (WINW - 1);  // 262081 output rows
  int nblocks = (T_out + ROWS_PER_BLK - 1) / ROWS_PER_BLK;  // 4096
  rolling_stats_kernel<<<nblocks, 256, 0, stream>>>(x, out, N, T_out);
}